// Round 1
// 210.553 us; speedup vs baseline: 1.0105x; 1.0105x over previous
//
#include <hip/hip_runtime.h>

#define TSEQ 512
#define NB   128
#define CDIM 384
#define HD   64
#define QSCALE 0.051031036307982884f   // 384^-0.5, folded into Q at projection
#define MBIAS  8.0f                    // fixed softmax offset (exact: cancels in O=PV/l)

typedef _Float16 half8  __attribute__((ext_vector_type(8)));
typedef _Float16 half4  __attribute__((ext_vector_type(4)));
typedef float    floatx4 __attribute__((ext_vector_type(4)));

typedef __attribute__((address_space(3))) unsigned int lds_u32;
typedef const __attribute__((address_space(1))) unsigned int g_u32;

__device__ __forceinline__ void load_lds16(const void* g, void* l) {
    // async global->LDS DMA, 16B/lane; LDS dst = wave-uniform base + lane*16
    __builtin_amdgcn_global_load_lds((g_u32*)g, (lds_u32*)l, 16, 0, 0);
}

// ---------------------------------------------------------------------------
// Kernel B: pack the three 384x64 fp32 weights into the EXACT per-chunk LDS
// staging order (12 chunks of BK=32):
//   Wp[c][kblk(4)][n(192)][kin(8)] = w_mat(n/64)[(c*32 + kblk*8 + kin)*64 + n%64]
// so qkv staging is 12 fully-contiguous 1-KB global_load_lds per chunk.
// ---------------------------------------------------------------------------
__global__ void prep_w(const float* __restrict__ wq, const float* __restrict__ wk,
                       const float* __restrict__ wv, _Float16* __restrict__ Wp)
{
    int i = blockIdx.x * 256 + threadIdx.x;
    if (i >= 3 * CDIM * HD) return;                 // 73728
    int c    = i / 6144;  int r  = i - c * 6144;    // chunk (BK=32)
    int kblk = r / 1536;  int r2 = r - kblk * 1536;
    int n    = r2 >> 3;   int kin = r2 & 7;
    int k    = c * 32 + kblk * 8 + kin;
    int mat  = n / 64;    int col = n - mat * 64;
    const float* w = (mat == 0) ? wq : ((mat == 1) ? wk : wv);
    Wp[i] = (_Float16)w[k * HD + col];
}

// ---------------------------------------------------------------------------
// Kernel C: fused QKV projection. Block = 64 rows x 192 cols, wave owns
// 16 rows x 192 cols (acc[12]). K in 12 chunks of BK=32, LDS double-buffered
// (2-phase: stage(c+1) overlaps compute(c); __syncthreads provides the
// vmcnt drain). Staging is transaction-optimal:
//   x : 2 instr/wave, 8 rows x 128 B contiguous each (full 64-B lines),
//       XOR-swizzled SOURCE (unit u holds global unit u^(m&7)) so the
//       linear-dest gload_lds still yields conflict-free A ds_reads.
//   W : 3 instr/wave, fully linear from the pre-packed Wp.
// Epilogue: bias + RoPE (fres==1 -> angle=t) via shfl_xor 1; Q scaled.
// Q,K (b,t,d) fp16; V transposed (b,d,t) fp16.
// ---------------------------------------------------------------------------
__global__ __launch_bounds__(256) void qkv_gemm(
    const float* __restrict__ x, const _Float16* __restrict__ Wp,
    const float* __restrict__ bq, const float* __restrict__ bk,
    const float* __restrict__ bv,
    _Float16* __restrict__ Qw, _Float16* __restrict__ Kw,
    _Float16* __restrict__ Vtw, int b0)
{
    __shared__ __align__(16) float    xs[2][64 * 32];   // 2 x 8 KB [m][32k]
    __shared__ __align__(16) _Float16 wsb[2][6144];     // 2 x 12 KB [kblk][n][8]

    const int tid  = threadIdx.x;
    const int wave = tid >> 6;
    const int lane = tid & 63;
    const int l16  = lane & 15;
    const int quad = lane >> 4;

    const int row0 = blockIdx.x * 64;                    // chunk-local row base
    const size_t rowg = (size_t)b0 * TSEQ + row0;        // global row base

    // ---- per-lane staging source offsets (constant across chunks) ----
    const int xr = lane >> 3;                            // row-in-group 0..7
    const int xu = lane & 7;                             // 16-B unit 0..7
    size_t xoff[2];
#pragma unroll
    for (int i = 0; i < 2; ++i) {
        const int m = (wave * 2 + i) * 8 + xr;           // m&7 == xr
        xoff[i] = (rowg + m) * CDIM + (size_t)((xu ^ xr) << 2);
    }
    int woff[3];
#pragma unroll
    for (int i = 0; i < 3; ++i) woff[i] = (wave * 3 + i) * 512 + lane * 8;

    floatx4 acc[12];
#pragma unroll
    for (int i = 0; i < 12; ++i)
#pragma unroll
        for (int r = 0; r < 4; ++r) acc[i][r] = 0.f;

#define STAGE(cc, bi) do {                                                    \
    _Pragma("unroll")                                                         \
    for (int i_ = 0; i_ < 2; ++i_)                                            \
        load_lds16(x + xoff[i_] + (cc) * 32,                                  \
                   (char*)&xs[bi][0] + (wave * 2 + i_) * 1024);               \
    _Pragma("unroll")                                                         \
    for (int i_ = 0; i_ < 3; ++i_)                                            \
        load_lds16(Wp + (cc) * 6144 + woff[i_],                               \
                   (char*)&wsb[bi][0] + (wave * 3 + i_) * 1024);              \
} while (0)

    STAGE(0, 0);
    __syncthreads();

#pragma unroll
    for (int c = 0; c < 12; ++c) {
        if (c < 11) STAGE(c + 1, (c + 1) & 1);           // prefetch next chunk

        const float*    xb = xs[c & 1];
        const _Float16* wb = wsb[c & 1];
        const int m  = wave * 16 + l16;
        const int mh = l16 & 7;                          // == m&7
        const int j0 = quad * 2;
        floatx4 a0 = *(const floatx4*)(xb + m * 32 + ((j0 ^ mh) << 2));
        floatx4 a1 = *(const floatx4*)(xb + m * 32 + (((j0 + 1) ^ mh) << 2));
        half8 a;
#pragma unroll
        for (int jj = 0; jj < 8; ++jj)
            a[jj] = (_Float16)(jj < 4 ? a0[jj] : a1[jj - 4]);
        const _Float16* bp = wb + ((size_t)quad * 192 + l16) * 8;
#pragma unroll
        for (int i = 0; i < 12; ++i) {
            half8 bb = *(const half8*)(bp + i * 128);
            acc[i] = __builtin_amdgcn_mfma_f32_16x16x32_f16(a, bb, acc[i], 0, 0, 0);
        }
        __syncthreads();
    }
#undef STAGE

    // ---- epilogue: bias + RoPE; Q/K row-major, V transposed (b,d,t) ----
    float bq4[4], bk4[4], bv4[4];
#pragma unroll
    for (int s4 = 0; s4 < 4; ++s4) {
        const int cc = s4 * 16 + l16;
        bq4[s4] = bq[cc]; bk4[s4] = bk[cc]; bv4[s4] = bv[cc];
    }
    const int t00  = (row0 & (TSEQ - 1)) + wave * 16 + quad * 4;
    const int bidx = row0 >> 9;                          // chunk-local batch
    const int rowb = row0 + wave * 16 + quad * 4;

#pragma unroll
    for (int r = 0; r < 4; ++r) {
        const int t = t00 + r;
        const float st = sinf((float)t);
        const float ct = cosf((float)t);
        const int row = rowb + r;
#pragma unroll
        for (int s4 = 0; s4 < 4; ++s4) {
            const int cc = s4 * 16 + l16;
            float vq = acc[s4][r] + bq4[s4];
            float pq = __shfl_xor(vq, 1);
            vq = (cc & 1) ? (pq * st + vq * ct) : (vq * ct - pq * st);
            Qw[(size_t)row * HD + cc] = (_Float16)(vq * QSCALE);
            float vk = acc[4 + s4][r] + bk4[s4];
            float pk = __shfl_xor(vk, 1);
            vk = (cc & 1) ? (pk * st + vk * ct) : (vk * ct - pk * st);
            Kw[(size_t)row * HD + cc] = (_Float16)vk;
        }
    }
    // V: pack 4 consecutive t per store (t = t00..t00+3 contiguous)
#pragma unroll
    for (int s4 = 0; s4 < 4; ++s4) {
        const int cc = s4 * 16 + l16;
        half4 vpack;
#pragma unroll
        for (int r = 0; r < 4; ++r) vpack[r] = (_Float16)(acc[8 + s4][r] + bv4[s4]);
        *(half4*)(Vtw + ((size_t)bidx * HD + cc) * TSEQ + t00) = vpack;
    }
}

// ---------------------------------------------------------------------------
// Kernel D: causal flash attention, reduction-free (fixed MBIAS -> partial
// O and L are exactly additive). Grid (8, nb) = 2 blocks/CU, 8 waves/CU.
// Per batch: 16 balanced strip PAIRS (s, 31-s) = constant 9 tile-units each;
// each pair's k-range is split even/odd j between two waves of the same
// block, merged through LDS at the end. All 512 blocks carry identical work.
// XCD swizzle keeps a batch's 8 blocks on one XCD (K/V stays in one L2).
// ---------------------------------------------------------------------------
__global__ __launch_bounds__(256) void attn_kernel(
    const _Float16* __restrict__ Qw, const _Float16* __restrict__ Kw,
    const _Float16* __restrict__ Vtw, float* __restrict__ out, int b0)
{
    int bx, bl;
    {
        const int lin = blockIdx.y * 8 + blockIdx.x;
        if ((gridDim.y & 7) == 0) {                  // bijective XCD grouping
            const int per = gridDim.y >> 3;          // batches per XCD
            const int xcd = lin & 7;
            const int k2  = lin >> 3;
            bl = xcd * per + (k2 >> 3);
            bx = k2 & 7;
        } else { bx = blockIdx.x; bl = blockIdx.y; }
    }
    const int tid  = threadIdx.x;
    const int wave = tid >> 6;
    const int lane = tid & 63;
    const int l16  = lane & 15;
    const int quad = lane >> 4;

    const int pr  = bx * 2 + (wave & 1);             // strip pair 0..15
    const int h   = wave >> 1;                       // k-half (even/odd j)
    const int qA  = pr * 16;                         // near strip rows
    const int qB  = (31 - pr) * 16;                  // far strip rows
    const int jdA = pr >> 2;                         // diag tile, strip A
    const int jdB = (31 - pr) >> 2;                  // diag tile, strip B

    __shared__ __align__(16) _Float16 pbuf[4][16][72];
    __shared__ __align__(16) floatx4  mbuf[2][10][64];   // merge buffer

    const _Float16* Qb = Qw  + (size_t)bl * TSEQ * HD;
    const _Float16* Kb = Kw  + (size_t)bl * TSEQ * HD;
    const _Float16* Vb = Vtw + (size_t)bl * HD * TSEQ;   // [d][t]

    half8 aQA0 = *(const half8*)(Qb + (size_t)(qA + l16) * HD + quad * 8);
    half8 aQA1 = *(const half8*)(Qb + (size_t)(qA + l16) * HD + 32 + quad * 8);
    half8 aQB0 = *(const half8*)(Qb + (size_t)(qB + l16) * HD + quad * 8);
    half8 aQB1 = *(const half8*)(Qb + (size_t)(qB + l16) * HD + 32 + quad * 8);

    half8 ones;
#pragma unroll
    for (int jj = 0; jj < 8; ++jj) ones[jj] = (_Float16)1.f;

    floatx4 accO[8], accL[2];
#pragma unroll
    for (int i = 0; i < 8; ++i)
#pragma unroll
        for (int r = 0; r < 4; ++r) accO[i][r] = 0.f;
#pragma unroll
    for (int s = 0; s < 2; ++s)
#pragma unroll
        for (int r = 0; r < 4; ++r) accL[s][r] = 0.f;

    for (int j = h; j <= jdB; j += 2) {
        const int kb = j * 64;

        // ---- shared K/V fragment loads (amortized across both strips) ----
        half8 bK0[4], bK1[4], bV0[4], bV1[4];
#pragma unroll
        for (int s4 = 0; s4 < 4; ++s4) {
            const _Float16* kp = Kb + (size_t)(kb + s4 * 16 + l16) * HD + quad * 8;
            bK0[s4] = *(const half8*)(kp);
            bK1[s4] = *(const half8*)(kp + 32);
            const _Float16* vp = Vb + (size_t)(s4 * 16 + l16) * TSEQ + kb + quad * 8;
            bV0[s4] = *(const half8*)(vp);
            bV1[s4] = *(const half8*)(vp + 32);
        }

        // ================= strip A (near; inactive past its diagonal) =====
        if (j <= jdA) {
            floatx4 st4[4];
            __builtin_amdgcn_s_setprio(1);
#pragma unroll
            for (int s4 = 0; s4 < 4; ++s4) {
#pragma unroll
                for (int r = 0; r < 4; ++r) st4[s4][r] = 0.f;
                st4[s4] = __builtin_amdgcn_mfma_f32_16x16x32_f16(bK0[s4], aQA0, st4[s4], 0, 0, 0);
                st4[s4] = __builtin_amdgcn_mfma_f32_16x16x32_f16(bK1[s4], aQA1, st4[s4], 0, 0, 0);
            }
            __builtin_amdgcn_s_setprio(0);
            const int qrow = qA + l16;
#pragma unroll
            for (int s4 = 0; s4 < 4; ++s4) {
                half4 w;
#pragma unroll
                for (int r = 0; r < 4; ++r) {
                    float p = __expf(fminf(st4[s4][r], 18.f) - MBIAS);
                    if (j == jdA) {
                        const int kcol = kb + s4 * 16 + quad * 4 + r;
                        if (kcol > qrow) p = 0.f;
                    }
                    w[r] = (_Float16)p;
                }
                *(half4*)(&pbuf[wave][l16][s4 * 16 + quad * 4]) = w;
            }
            half8 aP0 = *(const half8*)(&pbuf[wave][l16][quad * 8]);
            half8 aP1 = *(const half8*)(&pbuf[wave][l16][32 + quad * 8]);
            __builtin_amdgcn_s_setprio(1);
#pragma unroll
            for (int s4 = 0; s4 < 4; ++s4) {
                accO[s4] = __builtin_amdgcn_mfma_f32_16x16x32_f16(aP0, bV0[s4], accO[s4], 0, 0, 0);
                accO[s4] = __builtin_amdgcn_mfma_f32_16x16x32_f16(aP1, bV1[s4], accO[s4], 0, 0, 0);
            }
            accL[0] = __builtin_amdgcn_mfma_f32_16x16x32_f16(aP0, ones, accL[0], 0, 0, 0);
            accL[0] = __builtin_amdgcn_mfma_f32_16x16x32_f16(aP1, ones, accL[0], 0, 0, 0);
            __builtin_amdgcn_s_setprio(0);
        }

        // ================= strip B (far) ==================================
        {
            floatx4 st4[4];
            __builtin_amdgcn_s_setprio(1);
#pragma unroll
            for (int s4 = 0; s4 < 4; ++s4) {
#pragma unroll
                for (int r = 0; r < 4; ++r) st4[s4][r] = 0.f;
                st4[s4] = __builtin_amdgcn_mfma_f32_16x16x32_f16(bK0[s4], aQB0, st4[s4], 0, 0, 0);
                st4[s4] = __builtin_amdgcn_mfma_f32_16x16x32_f16(bK1[s4], aQB1, st4[s4], 0, 0, 0);
            }
            __builtin_amdgcn_s_setprio(0);
            const int qrow = qB + l16;
#pragma unroll
            for (int s4 = 0; s4 < 4; ++s4) {
                half4 w;
#pragma unroll
                for (int r = 0; r < 4; ++r) {
                    float p = __expf(fminf(st4[s4][r], 18.f) - MBIAS);
                    if (j == jdB) {
                        const int kcol = kb + s4 * 16 + quad * 4 + r;
                        if (kcol > qrow) p = 0.f;
                    }
                    w[r] = (_Float16)p;
                }
                *(half4*)(&pbuf[wave][l16][s4 * 16 + quad * 4]) = w;
            }
            half8 aP0 = *(const half8*)(&pbuf[wave][l16][quad * 8]);
            half8 aP1 = *(const half8*)(&pbuf[wave][l16][32 + quad * 8]);
            __builtin_amdgcn_s_setprio(1);
#pragma unroll
            for (int s4 = 0; s4 < 4; ++s4) {
                accO[4 + s4] = __builtin_amdgcn_mfma_f32_16x16x32_f16(aP0, bV0[s4], accO[4 + s4], 0, 0, 0);
                accO[4 + s4] = __builtin_amdgcn_mfma_f32_16x16x32_f16(aP1, bV1[s4], accO[4 + s4], 0, 0, 0);
            }
            accL[1] = __builtin_amdgcn_mfma_f32_16x16x32_f16(aP0, ones, accL[1], 0, 0, 0);
            accL[1] = __builtin_amdgcn_mfma_f32_16x16x32_f16(aP1, ones, accL[1], 0, 0, 0);
            __builtin_amdgcn_s_setprio(0);
        }
    }

    // ---- merge the two k-halves of each pair (exact: fixed-bias softmax) --
    const int slot = wave & 1;
    if (h == 1) {
#pragma unroll
        for (int i = 0; i < 8; ++i) mbuf[slot][i][lane] = accO[i];
        mbuf[slot][8][lane] = accL[0];
        mbuf[slot][9][lane] = accL[1];
    }
    __syncthreads();
    if (h == 1) return;

#pragma unroll
    for (int i = 0; i < 8; ++i) {
        floatx4 t = mbuf[slot][i][lane];
#pragma unroll
        for (int r = 0; r < 4; ++r) accO[i][r] += t[r];
    }
    {
        floatx4 t8 = mbuf[slot][8][lane];
        floatx4 t9 = mbuf[slot][9][lane];
#pragma unroll
        for (int r = 0; r < 4; ++r) { accL[0][r] += t8[r]; accL[1][r] += t9[r]; }
    }

    // ---- epilogue (h==0 wave writes both strips) ----
#pragma unroll
    for (int s = 0; s < 2; ++s) {
        const int qbase = (s == 0) ? qA : qB;
        float inv[4];
#pragma unroll
        for (int r = 0; r < 4; ++r) inv[r] = 1.f / accL[s][r];
#pragma unroll
        for (int s4 = 0; s4 < 4; ++s4) {
            const int dcol = s4 * 16 + l16;
#pragma unroll
            for (int r = 0; r < 4; ++r) {
                const int qr = qbase + quad * 4 + r;
                out[((size_t)(b0 + bl) * TSEQ + qr) * HD + dcol] =
                    accO[s * 4 + s4][r] * inv[r];
            }
        }
    }
}

// ---------------------------------------------------------------------------
extern "C" void kernel_launch(void* const* d_in, const int* in_sizes, int n_in,
                              void* d_out, int out_size, void* d_ws, size_t ws_size,
                              hipStream_t stream)
{
    char* ws = (char*)d_ws;
    _Float16* Wp = (_Float16*)ws;                           // 147456 B
    char* qkv_base = ws + 147456;

    const size_t per_b = (size_t)3 * TSEQ * HD * sizeof(_Float16);  // 196608 B
    size_t avail = (ws_size > (size_t)147456) ? ws_size - 147456 : per_b;
    int nbc = (int)(avail / per_b);
    if (nbc > NB) nbc = NB;
    if (nbc < 1)  nbc = 1;

    const size_t chunk_elems = (size_t)nbc * TSEQ * HD;
    _Float16* Qw  = (_Float16*)qkv_base;
    _Float16* Kw  = Qw + chunk_elems;
    _Float16* Vtw = Kw + chunk_elems;

    prep_w<<<dim3((3 * CDIM * HD + 255) / 256), dim3(256), 0, stream>>>(
        (const float*)d_in[1], (const float*)d_in[3], (const float*)d_in[5], Wp);

    for (int b0 = 0; b0 < NB; b0 += nbc) {
        const int nb = (NB - b0 < nbc) ? (NB - b0) : nbc;
        qkv_gemm<<<dim3(nb * 8), dim3(256), 0, stream>>>(
            (const float*)d_in[0], Wp, (const float*)d_in[2], (const float*)d_in[4],
            (const float*)d_in[6], Qw, Kw, Vtw, b0);
        attn_kernel<<<dim3(8, nb), dim3(256), 0, stream>>>(
            Qw, Kw, Vtw, (float*)d_out, b0);
    }
}